// Round 6
// baseline (281.539 us; speedup 1.0000x reference)
//
#include <hip/hip_runtime.h>
#include <hip/hip_bf16.h>
#include <float.h>
#include <math.h>

// B=4, S=4096, D=2048, E=64, K=2
#define B_DIM 4
#define S_DIM 4096
#define D_DIM 2048
#define E_DIM 64
#define N_TOK 16384
#define SPLITK 8
#define KSLICE (D_DIM / SPLITK)      // 256
#define STEPS (KSLICE / 32)          // 8
#define TPB_MAIN 128                 // tokens per main block (8 waves x 16)
#define NMAIN ((N_TOK / TPB_MAIN) * SPLITK)   // 1024 blocks = 4/CU -> 32 waves/CU
#define EPB 16                       // tokens per epilogue block (16 waves)
#define NEPI (N_TOK / EPB)           // 1024
#define PITCH 264                    // ushort pitch (528 B): stride 132 dw = 4 mod 32 (uniform banks)
#define GAP_THRESH 0.02f             // ~12 sigma of bf16 y-error

// d_ws layout (all regions fully written every launch -> no memset needed):
// [0, 4K) blkz[1024]; [4K, 268K) blkload[1024][64]; [268K, +32M) partials
#define WS_BLKLOAD_B 4096
#define WS_PART_B    (4096 + 262144)
#define WS_NEED      (WS_PART_B + (size_t)SPLITK * N_TOK * E_DIM * 4)

typedef __bf16 bf16x8_t __attribute__((ext_vector_type(8)));
typedef float f32x4_t __attribute__((ext_vector_type(4)));
union U8 { bf16x8_t v; unsigned short u[8]; };

__device__ __forceinline__ unsigned short f2bf(float f) {   // RNE fp32->bf16
    unsigned int u = __float_as_uint(f);
    u += 0x7FFFu + ((u >> 16) & 1u);
    return (unsigned short)(u >> 16);
}

// Main GEMM: 512 thr (8 waves), W-slice (64x256 bf16, 33.8 KB LDS) staged once,
// then barrier-free. 4 blocks/CU = 8 waves/SIMD for latency hiding.
template<bool ATOMIC>
__global__ __launch_bounds__(512, 8) void router_main(
    const float* __restrict__ x, const float* __restrict__ W,
    float* __restrict__ part)  // store: [SPLITK][N_TOK][64]; atomic: [N_TOK][64]
{
    __shared__ unsigned short wlds[E_DIM][PITCH];
    const int tid = threadIdx.x;
    const int slice = blockIdx.x & (SPLITK - 1);
    const int grp = blockIdx.x >> 3;

    // stage W slice (64 rows x 256 cols) as bf16: 8 threads/row, 32 cols each
    {
        const int row = tid >> 3, seg = tid & 7;
        const float* wp = W + (size_t)row * D_DIM + slice * KSLICE + seg * 32;
        #pragma unroll
        for (int j = 0; j < 8; ++j) {
            float4 v = *(const float4*)(wp + j * 4);
            ushort4 h = {f2bf(v.x), f2bf(v.y), f2bf(v.z), f2bf(v.w)};
            *(ushort4*)&wlds[row][seg * 32 + j * 4] = h;
        }
    }
    __syncthreads();

    const int lane = tid & 63, wv = tid >> 6;
    const int l15 = lane & 15, quad = lane >> 4;
    const int token0 = grp * TPB_MAIN + wv * 16;
    const float* xp = x + (size_t)(token0 + l15) * D_DIM + slice * KSLICE + quad * 8;

    f32x4_t acc[4];
    #pragma unroll
    for (int t = 0; t < 4; ++t) acc[t] = (f32x4_t){0.f, 0.f, 0.f, 0.f};

    float4 xq0 = *(const float4*)xp;
    float4 xq1 = *(const float4*)(xp + 4);
    #pragma unroll
    for (int s = 0; s < STEPS; ++s) {
        float4 xn0, xn1;
        if (s + 1 < STEPS) {                       // prefetch next x fragment
            xn0 = *(const float4*)(xp + (s + 1) * 32);
            xn1 = *(const float4*)(xp + (s + 1) * 32 + 4);
        }
        U8 a;
        a.u[0] = f2bf(xq0.x); a.u[1] = f2bf(xq0.y); a.u[2] = f2bf(xq0.z); a.u[3] = f2bf(xq0.w);
        a.u[4] = f2bf(xq1.x); a.u[5] = f2bf(xq1.y); a.u[6] = f2bf(xq1.z); a.u[7] = f2bf(xq1.w);
        #pragma unroll
        for (int t = 0; t < 4; ++t) {
            bf16x8_t b = *(const bf16x8_t*)&wlds[t * 16 + l15][s * 32 + quad * 8];
            acc[t] = __builtin_amdgcn_mfma_f32_16x16x32_bf16(a.v, b, acc[t], 0, 0, 0);
        }
        if (s + 1 < STEPS) { xq0 = xn0; xq1 = xn1; }
    }

    // C/D layout: col(expert)=lane&15, row(token)=quad*4+r (verified r1-r5)
    #pragma unroll
    for (int t = 0; t < 4; ++t)
        #pragma unroll
        for (int r = 0; r < 4; ++r) {
            const int token = token0 + quad * 4 + r;
            const int e = t * 16 + l15;
            if (ATOMIC) atomicAdd(&part[(size_t)token * E_DIM + e], acc[t][r]);
            else part[((size_t)slice * N_TOK + token) * E_DIM + e] = acc[t][r];
        }
}

__device__ __forceinline__ void wave_argmax(float y, float& mv, int& mi) {
    float v = y; int ix = threadIdx.x & 63;
    #pragma unroll
    for (int d = 32; d; d >>= 1) {
        float ov = __shfl_xor(v, d); int oi = __shfl_xor(ix, d);
        if (ov > v || (ov == v && oi < ix)) { v = ov; ix = oi; }
    }
    mv = v; mi = ix;   // all lanes hold result
}

// Epilogue: 1024 thr = 16 waves = 16 tokens; lane = expert.
// No global atomics: block-level LDS reduction + plain stores to blkz/blkload.
template<bool ATOMIC>
__global__ __launch_bounds__(1024, 2) void router_epi(
    const float* __restrict__ part, const float* __restrict__ x,
    const float* __restrict__ W, const float* __restrict__ gamma,
    const float* __restrict__ beta, const float* __restrict__ temperature,
    float* __restrict__ out_rw, float* __restrict__ out_dp,
    float* __restrict__ blkz, float* __restrict__ blkload)
{
    __shared__ float zred[EPB];
    __shared__ float loadshared[E_DIM];
    const int tid = threadIdx.x;
    const int lane = tid & 63, wv = tid >> 6;
    const int tok = blockIdx.x * EPB + wv;
    if (tid < E_DIM) loadshared[tid] = 0.f;
    __syncthreads();

    float p;
    if (ATOMIC) p = part[(size_t)tok * E_DIM + lane];
    else {
        p = 0.f;
        #pragma unroll
        for (int s = 0; s < SPLITK; ++s) p += part[((size_t)s * N_TOK + tok) * E_DIM + lane];
    }
    // LayerNorm over 64 experts (biased var, eps=1e-5)
    float s1 = p, s2 = p * p;
    #pragma unroll
    for (int d = 32; d; d >>= 1) { s1 += __shfl_xor(s1, d); s2 += __shfl_xor(s2, d); }
    const float mu = s1 * (1.f / 64.f);
    const float var = s2 * (1.f / 64.f) - mu * mu;
    const float rs = rsqrtf(var + 1e-5f);
    const float y = (p - mu) * rs * gamma[lane] + beta[lane];

    float zl = y * y;
    #pragma unroll
    for (int d = 32; d; d >>= 1) zl += __shfl_xor(zl, d);
    if (lane == 0) zred[wv] = zl;

    // top-4 via iterative masked argmax (low-index tie-break = lax.top_k)
    float m0, m1, m2, m3; int i0, i1, i2, i3;
    wave_argmax(y, m0, i0);
    wave_argmax((lane == i0) ? -FLT_MAX : y, m1, i1);
    wave_argmax((lane == i0 || lane == i1) ? -FLT_MAX : y, m2, i2);
    wave_argmax((lane == i0 || lane == i1 || lane == i2) ? -FLT_MAX : y, m3, i3);
    int sa = i0, sb = i1;

    if (m1 - m2 < GAP_THRESH) {   // near-tie at the 2|3 boundary: fp64 re-rank top-4
        const float* xr = x + (size_t)tok * D_DIM;
        const int cc[4] = {i0, i1, i2, i3};
        double yy[4];
        #pragma unroll
        for (int j = 0; j < 4; ++j) {
            const float* wr = W + (size_t)cc[j] * D_DIM;
            double a = 0.0;
            for (int i = lane; i < D_DIM; i += 64) a += (double)xr[i] * (double)wr[i];
            #pragma unroll
            for (int d = 32; d; d >>= 1) a += __shfl_xor(a, d);
            yy[j] = (a - (double)mu) * (double)rs * (double)gamma[cc[j]] + (double)beta[cc[j]];
        }
        int a4 = 0;
        #pragma unroll
        for (int j = 1; j < 4; ++j)
            if (yy[j] > yy[a4] || (yy[j] == yy[a4] && cc[j] < cc[a4])) a4 = j;
        int b4 = (a4 == 0) ? 1 : 0;
        #pragma unroll
        for (int j = 0; j < 4; ++j)
            if (j != a4 && (yy[j] > yy[b4] || (yy[j] == yy[b4] && cc[j] < cc[b4]))) b4 = j;
        sa = cc[a4]; sb = cc[b4];
    }

    // temperature softmax
    const float it = 1.f / (temperature[0] + 1e-6f);
    float ev = __expf((y - m0) * it);
    float es = ev;
    #pragma unroll
    for (int d = 32; d; d >>= 1) es += __shfl_xor(es, d);
    const float prob = ev / es;

    out_rw[(size_t)tok * E_DIM + lane] = prob;
    const bool sel = (lane == sa || lane == sb);
    out_dp[(size_t)tok * E_DIM + lane] = sel ? prob : 0.f;
    if (sel) atomicAdd(&loadshared[lane], prob);   // LDS atomic: 32 adds / 64 addrs
    __syncthreads();

    if (tid < E_DIM) blkload[((size_t)blockIdx.x << 6) | tid] = loadshared[tid];
    if (tid == 0) {
        float z = 0.f;
        #pragma unroll
        for (int i = 0; i < EPB; ++i) z += zred[i];
        blkz[blockIdx.x] = z;
    }
}

// Final reduce: blkload [1024][64] -> expert_load[4][64]; blkz[1024] -> z sum.
__global__ __launch_bounds__(256) void router_fin(
    const float* __restrict__ blkz, const float* __restrict__ blkload,
    float* __restrict__ out_loss)
{
    __shared__ float sv[B_DIM * E_DIM];
    __shared__ float zw[4];
    const int t = threadIdx.x;
    const int b = t >> 6, e = t & 63;
    float s = 0.f;
    for (int j = 0; j < NEPI / B_DIM; ++j)           // 256 blocks per batch
        s += blkload[(((size_t)b * (NEPI / B_DIM) + j) << 6) | e];
    sv[t] = s * (1.f / S_DIM);                       // expert_load[b][e]
    float z = 0.f;
    #pragma unroll
    for (int j = 0; j < 4; ++j) z += blkz[t * 4 + j];
    #pragma unroll
    for (int d = 32; d; d >>= 1) z += __shfl_xor(z, d);
    if ((t & 63) == 0) zw[t >> 6] = z;
    __syncthreads();
    if (t == 0) {
        const float ztot = zw[0] + zw[1] + zw[2] + zw[3];
        float tt = 0.f;
        for (int i = 0; i < B_DIM * E_DIM; ++i) tt += sv[i];
        const float mean = tt * (1.f / (B_DIM * E_DIM));
        float ss = 0.f;
        for (int i = 0; i < B_DIM * E_DIM; ++i) { float d = sv[i] - mean; ss += d * d; }
        const float sd = sqrtf(ss * (1.f / (B_DIM * E_DIM - 1)));  // ddof=1
        out_loss[0] = 0.001f * (ztot * (1.f / ((float)N_TOK * E_DIM)))
                    + 0.1f * (sd / mean) * 10.f;
    }
}

extern "C" void kernel_launch(void* const* d_in, const int* in_sizes, int n_in,
                              void* d_out, int out_size, void* d_ws, size_t ws_size,
                              hipStream_t stream) {
    const float* x     = (const float*)d_in[0];
    const float* W     = (const float*)d_in[1];
    const float* gamma = (const float*)d_in[2];
    const float* beta  = (const float*)d_in[3];
    const float* temp  = (const float*)d_in[4];
    float* out  = (float*)d_out;
    float* rw   = out;
    float* dp   = out + (size_t)N_TOK * E_DIM;
    float* loss = out + 2 * (size_t)N_TOK * E_DIM;

    float* blkz    = (float*)d_ws;
    float* blkload = (float*)((char*)d_ws + WS_BLKLOAD_B);
    float* partbuf = (float*)((char*)d_ws + WS_PART_B);
    const bool store_path = (ws_size >= WS_NEED);

    if (store_path) {
        // no memsets: partials, blkz, blkload fully overwritten every launch
        router_main<false><<<dim3(NMAIN), dim3(512), 0, stream>>>(x, W, partbuf);
        router_epi<false><<<dim3(NEPI), dim3(1024), 0, stream>>>(
            partbuf, x, W, gamma, beta, temp, rw, dp, blkz, blkload);
    } else {
        hipMemsetAsync(rw, 0, (size_t)N_TOK * E_DIM * 4, stream);
        router_main<true><<<dim3(NMAIN), dim3(512), 0, stream>>>(x, W, rw);
        router_epi<true><<<dim3(NEPI), dim3(1024), 0, stream>>>(
            rw, x, W, gamma, beta, temp, rw, dp, blkz, blkload);
    }
    router_fin<<<dim3(1), dim3(256), 0, stream>>>(blkz, blkload, loss);
}

// Round 7
// 277.713 us; speedup vs baseline: 1.0138x; 1.0138x over previous
//
#include <hip/hip_runtime.h>
#include <hip/hip_bf16.h>
#include <float.h>
#include <math.h>

// B=4, S=4096, D=2048, E=64, K=2
#define B_DIM 4
#define S_DIM 4096
#define D_DIM 2048
#define E_DIM 64
#define N_TOK 16384
#define SPLITK 8
#define KSLICE (D_DIM / SPLITK)      // 256
#define STEPS (KSLICE / 32)          // 8
#define TPB_MAIN 128                 // tokens per main block (8 waves x 16)
#define NMAIN ((N_TOK / TPB_MAIN) * SPLITK)   // 1024 blocks
#define EPB 16                       // tokens per epilogue block (16 waves)
#define NEPI (N_TOK / EPB)           // 1024
#define PITCH 264                    // ushort pitch (528 B)
#define GAP_THRESH 0.02f             // ~12 sigma of bf16 y-error

// d_ws layout (fully written every launch -> no memset needed):
// [0, 4K) blkz[1024]; [4K, 268K) blkload[1024][64]; [268K, +32M) partials
#define WS_BLKLOAD_B 4096
#define WS_PART_B    (4096 + 262144)
#define WS_NEED      (WS_PART_B + (size_t)SPLITK * N_TOK * E_DIM * 4)

typedef __bf16 bf16x8_t __attribute__((ext_vector_type(8)));
typedef float f32x4_t __attribute__((ext_vector_type(4)));
union U8 { bf16x8_t v; unsigned short u[8]; };

__device__ __forceinline__ unsigned short f2bf(float f) {   // RNE fp32->bf16
    unsigned int u = __float_as_uint(f);
    u += 0x7FFFu + ((u >> 16) & 1u);
    return (unsigned short)(u >> 16);
}

// Main GEMM: 512 thr (8 waves), W-slice (64x256 bf16, 33 KB LDS) staged once.
// Each wave loads its ENTIRE x K-slice up front (16 independent float4 = one
// memory round-trip, deep MLP) then runs 8 MFMA steps with progressive vmcnt.
// launch_bounds(512,4): <=128 VGPR (no spill at ~115 live), 2 blocks/CU.
template<bool ATOMIC>
__global__ __launch_bounds__(512, 4) void router_main(
    const float* __restrict__ x, const float* __restrict__ W,
    float* __restrict__ part)  // store: [SPLITK][N_TOK][64]; atomic: [N_TOK][64]
{
    __shared__ unsigned short wlds[E_DIM][PITCH];
    const int tid = threadIdx.x;
    const int slice = blockIdx.x & (SPLITK - 1);
    const int grp = blockIdx.x >> 3;

    const int lane = tid & 63, wv = tid >> 6;
    const int l15 = lane & 15, quad = lane >> 4;
    const int token0 = grp * TPB_MAIN + wv * 16;
    const float* xp = x + (size_t)(token0 + l15) * D_DIM + slice * KSLICE + quad * 8;

    // issue ALL x loads for this wave's K-slice first (16 independent float4)
    float4 xr[16];
    #pragma unroll
    for (int j = 0; j < 16; ++j)
        xr[j] = *(const float4*)(xp + (j >> 1) * 32 + (j & 1) * 4);

    // stage W slice (64 rows x 256 cols) as bf16: 8 threads/row, 32 cols each
    {
        const int row = tid >> 3, seg = tid & 7;
        const float* wp = W + (size_t)row * D_DIM + slice * KSLICE + seg * 32;
        #pragma unroll
        for (int j = 0; j < 8; ++j) {
            float4 v = *(const float4*)(wp + j * 4);
            ushort4 h = {f2bf(v.x), f2bf(v.y), f2bf(v.z), f2bf(v.w)};
            *(ushort4*)&wlds[row][seg * 32 + j * 4] = h;
        }
    }
    __syncthreads();

    f32x4_t acc[4];
    #pragma unroll
    for (int t = 0; t < 4; ++t) acc[t] = (f32x4_t){0.f, 0.f, 0.f, 0.f};

    #pragma unroll
    for (int s = 0; s < STEPS; ++s) {
        U8 a;
        a.u[0] = f2bf(xr[2*s].x);   a.u[1] = f2bf(xr[2*s].y);
        a.u[2] = f2bf(xr[2*s].z);   a.u[3] = f2bf(xr[2*s].w);
        a.u[4] = f2bf(xr[2*s+1].x); a.u[5] = f2bf(xr[2*s+1].y);
        a.u[6] = f2bf(xr[2*s+1].z); a.u[7] = f2bf(xr[2*s+1].w);
        #pragma unroll
        for (int t = 0; t < 4; ++t) {
            bf16x8_t b = *(const bf16x8_t*)&wlds[t * 16 + l15][s * 32 + quad * 8];
            acc[t] = __builtin_amdgcn_mfma_f32_16x16x32_bf16(a.v, b, acc[t], 0, 0, 0);
        }
    }

    // C/D layout: col(expert)=lane&15, row(token)=quad*4+r (verified r1-r6)
    #pragma unroll
    for (int t = 0; t < 4; ++t)
        #pragma unroll
        for (int r = 0; r < 4; ++r) {
            const int token = token0 + quad * 4 + r;
            const int e = t * 16 + l15;
            if (ATOMIC) atomicAdd(&part[(size_t)token * E_DIM + e], acc[t][r]);
            else part[((size_t)slice * N_TOK + token) * E_DIM + e] = acc[t][r];
        }
}

__device__ __forceinline__ void wave_argmax(float y, float& mv, int& mi) {
    float v = y; int ix = threadIdx.x & 63;
    #pragma unroll
    for (int d = 32; d; d >>= 1) {
        float ov = __shfl_xor(v, d); int oi = __shfl_xor(ix, d);
        if (ov > v || (ov == v && oi < ix)) { v = ov; ix = oi; }
    }
    mv = v; mi = ix;   // all lanes hold result
}

// Epilogue: 1024 thr = 16 waves = 16 tokens; lane = expert.
// No global atomics: block-level LDS reduction + plain stores to blkz/blkload.
template<bool ATOMIC>
__global__ __launch_bounds__(1024, 2) void router_epi(
    const float* __restrict__ part, const float* __restrict__ x,
    const float* __restrict__ W, const float* __restrict__ gamma,
    const float* __restrict__ beta, const float* __restrict__ temperature,
    float* __restrict__ out_rw, float* __restrict__ out_dp,
    float* __restrict__ blkz, float* __restrict__ blkload)
{
    __shared__ float zred[EPB];
    __shared__ float loadshared[E_DIM];
    const int tid = threadIdx.x;
    const int lane = tid & 63, wv = tid >> 6;
    const int tok = blockIdx.x * EPB + wv;
    if (tid < E_DIM) loadshared[tid] = 0.f;
    __syncthreads();

    float p;
    if (ATOMIC) p = part[(size_t)tok * E_DIM + lane];
    else {
        p = 0.f;
        #pragma unroll
        for (int s = 0; s < SPLITK; ++s) p += part[((size_t)s * N_TOK + tok) * E_DIM + lane];
    }
    // LayerNorm over 64 experts (biased var, eps=1e-5)
    float s1 = p, s2 = p * p;
    #pragma unroll
    for (int d = 32; d; d >>= 1) { s1 += __shfl_xor(s1, d); s2 += __shfl_xor(s2, d); }
    const float mu = s1 * (1.f / 64.f);
    const float var = s2 * (1.f / 64.f) - mu * mu;
    const float rs = rsqrtf(var + 1e-5f);
    const float y = (p - mu) * rs * gamma[lane] + beta[lane];

    float zl = y * y;
    #pragma unroll
    for (int d = 32; d; d >>= 1) zl += __shfl_xor(zl, d);
    if (lane == 0) zred[wv] = zl;

    // top-4 via iterative masked argmax (low-index tie-break = lax.top_k)
    float m0, m1, m2, m3; int i0, i1, i2, i3;
    wave_argmax(y, m0, i0);
    wave_argmax((lane == i0) ? -FLT_MAX : y, m1, i1);
    wave_argmax((lane == i0 || lane == i1) ? -FLT_MAX : y, m2, i2);
    wave_argmax((lane == i0 || lane == i1 || lane == i2) ? -FLT_MAX : y, m3, i3);
    int sa = i0, sb = i1;

    if (m1 - m2 < GAP_THRESH) {   // near-tie at the 2|3 boundary: fp64 re-rank top-4
        const float* xr = x + (size_t)tok * D_DIM;
        const int cc[4] = {i0, i1, i2, i3};
        double yy[4];
        #pragma unroll
        for (int j = 0; j < 4; ++j) {
            const float* wr = W + (size_t)cc[j] * D_DIM;
            double a = 0.0;
            for (int i = lane; i < D_DIM; i += 64) a += (double)xr[i] * (double)wr[i];
            #pragma unroll
            for (int d = 32; d; d >>= 1) a += __shfl_xor(a, d);
            yy[j] = (a - (double)mu) * (double)rs * (double)gamma[cc[j]] + (double)beta[cc[j]];
        }
        int a4 = 0;
        #pragma unroll
        for (int j = 1; j < 4; ++j)
            if (yy[j] > yy[a4] || (yy[j] == yy[a4] && cc[j] < cc[a4])) a4 = j;
        int b4 = (a4 == 0) ? 1 : 0;
        #pragma unroll
        for (int j = 0; j < 4; ++j)
            if (j != a4 && (yy[j] > yy[b4] || (yy[j] == yy[b4] && cc[j] < cc[b4]))) b4 = j;
        sa = cc[a4]; sb = cc[b4];
    }

    // temperature softmax
    const float it = 1.f / (temperature[0] + 1e-6f);
    float ev = __expf((y - m0) * it);
    float es = ev;
    #pragma unroll
    for (int d = 32; d; d >>= 1) es += __shfl_xor(es, d);
    const float prob = ev / es;

    out_rw[(size_t)tok * E_DIM + lane] = prob;
    const bool sel = (lane == sa || lane == sb);
    out_dp[(size_t)tok * E_DIM + lane] = sel ? prob : 0.f;
    if (sel) atomicAdd(&loadshared[lane], prob);   // LDS atomic: 32 adds / 64 addrs
    __syncthreads();

    if (tid < E_DIM) blkload[((size_t)blockIdx.x << 6) | tid] = loadshared[tid];
    if (tid == 0) {
        float z = 0.f;
        #pragma unroll
        for (int i = 0; i < EPB; ++i) z += zred[i];
        blkz[blockIdx.x] = z;
    }
}

// Final reduce: blkload [1024][64] -> expert_load[4][64]; blkz[1024] -> z sum.
__global__ __launch_bounds__(256) void router_fin(
    const float* __restrict__ blkz, const float* __restrict__ blkload,
    float* __restrict__ out_loss)
{
    __shared__ float sv[B_DIM * E_DIM];
    __shared__ float zw[4];
    const int t = threadIdx.x;
    const int b = t >> 6, e = t & 63;
    float s = 0.f;
    for (int j = 0; j < NEPI / B_DIM; ++j)           // 256 blocks per batch
        s += blkload[(((size_t)b * (NEPI / B_DIM) + j) << 6) | e];
    sv[t] = s * (1.f / S_DIM);                       // expert_load[b][e]
    float z = 0.f;
    #pragma unroll
    for (int j = 0; j < 4; ++j) z += blkz[t * 4 + j];
    #pragma unroll
    for (int d = 32; d; d >>= 1) z += __shfl_xor(z, d);
    if ((t & 63) == 0) zw[t >> 6] = z;
    __syncthreads();
    if (t == 0) {
        const float ztot = zw[0] + zw[1] + zw[2] + zw[3];
        float tt = 0.f;
        for (int i = 0; i < B_DIM * E_DIM; ++i) tt += sv[i];
        const float mean = tt * (1.f / (B_DIM * E_DIM));
        float ss = 0.f;
        for (int i = 0; i < B_DIM * E_DIM; ++i) { float d = sv[i] - mean; ss += d * d; }
        const float sd = sqrtf(ss * (1.f / (B_DIM * E_DIM - 1)));  // ddof=1
        out_loss[0] = 0.001f * (ztot * (1.f / ((float)N_TOK * E_DIM)))
                    + 0.1f * (sd / mean) * 10.f;
    }
}

extern "C" void kernel_launch(void* const* d_in, const int* in_sizes, int n_in,
                              void* d_out, int out_size, void* d_ws, size_t ws_size,
                              hipStream_t stream) {
    const float* x     = (const float*)d_in[0];
    const float* W     = (const float*)d_in[1];
    const float* gamma = (const float*)d_in[2];
    const float* beta  = (const float*)d_in[3];
    const float* temp  = (const float*)d_in[4];
    float* out  = (float*)d_out;
    float* rw   = out;
    float* dp   = out + (size_t)N_TOK * E_DIM;
    float* loss = out + 2 * (size_t)N_TOK * E_DIM;

    float* blkz    = (float*)d_ws;
    float* blkload = (float*)((char*)d_ws + WS_BLKLOAD_B);
    float* partbuf = (float*)((char*)d_ws + WS_PART_B);
    const bool store_path = (ws_size >= WS_NEED);

    if (store_path) {
        // no memsets: partials, blkz, blkload fully overwritten every launch
        router_main<false><<<dim3(NMAIN), dim3(512), 0, stream>>>(x, W, partbuf);
        router_epi<false><<<dim3(NEPI), dim3(1024), 0, stream>>>(
            partbuf, x, W, gamma, beta, temp, rw, dp, blkz, blkload);
    } else {
        hipMemsetAsync(rw, 0, (size_t)N_TOK * E_DIM * 4, stream);
        router_main<true><<<dim3(NMAIN), dim3(512), 0, stream>>>(x, W, rw);
        router_epi<true><<<dim3(NEPI), dim3(1024), 0, stream>>>(
            rw, x, W, gamma, beta, temp, rw, dp, blkz, blkload);
    }
    router_fin<<<dim3(1), dim3(256), 0, stream>>>(blkz, blkload, loss);
}